// Round 1
// baseline (426.843 us; speedup 1.0000x reference)
//
#include <hip/hip_runtime.h>

typedef unsigned short u16;

#define M_ROWS 8192
#define N_ROWS 16384
#define KDIM   512
#define NCHUNKS 8
#define NPER   (N_ROWS / NCHUNKS)   /* 2048 */
#define TOPK   9

#define BNT 256                     /* n rows per tile (mb, MFMA-A side) */
#define BMT 256                     /* m cols per block (fv, MFMA-B side) */
#define BKT 32                      /* K per LDS tile */
#define NT  (NPER / BNT)            /* 8  n-tiles per block */
#define KT  (KDIM / BKT)            /* 16 K-tiles per n-tile */

typedef __attribute__((ext_vector_type(8))) short bf16x8;
typedef __attribute__((ext_vector_type(4))) float f32x4;

__device__ __forceinline__ void gload_lds16(const void* gp, void* lp) {
  __builtin_amdgcn_global_load_lds(
      (const __attribute__((address_space(1))) void*)gp,
      (__attribute__((address_space(3))) void*)lp,
      16, 0, 0);
}

__device__ __forceinline__ u16 f2bf(float x) {
  union { float f; unsigned u; } c; c.f = x;
  unsigned u = c.u;
  u += 0x7fffu + ((u >> 16) & 1u);   // RNE; inputs finite randn
  return (u16)(u >> 16);
}

__device__ __forceinline__ void topk_update(float v, float* best) {
  if (v < best[TOPK - 1]) {
    #pragma unroll
    for (int i = 0; i < TOPK; ++i) {
      float b = best[i];
      best[i] = fminf(b, v);
      v = fmaxf(b, v);
    }
  }
}

// ---- Kernel 1: fp32 -> bf16 convert + fp32 row norms (nm now in PLAIN order:
//      16x16x32 C-rows are consecutive, so the epilogue reads nm as float4).
__global__ __launch_bounds__(256) void prep_kernel(
    const float* __restrict__ fv, const float* __restrict__ mb,
    u16* __restrict__ fvb, u16* __restrict__ mbb,
    float* __restrict__ nf, float* __restrict__ nm)
{
  int idx = blockIdx.x * 4 + (threadIdx.x >> 6);   // one wave per row
  int l = threadIdx.x & 63;
  const float* src; u16* dst;
  if (idx < M_ROWS) {
    src = fv + (size_t)idx * KDIM; dst = fvb + (size_t)idx * KDIM;
  } else {
    int r = idx - M_ROWS;
    src = mb + (size_t)r * KDIM; dst = mbb + (size_t)r * KDIM;
  }
  float4 x0 = ((const float4*)src)[2 * l];
  float4 x1 = ((const float4*)src)[2 * l + 1];
  float s = x0.x * x0.x + x0.y * x0.y + x0.z * x0.z + x0.w * x0.w
          + x1.x * x1.x + x1.y * x1.y + x1.z * x1.z + x1.w * x1.w;
  uint4 o;
  o.x = (unsigned)f2bf(x0.x) | ((unsigned)f2bf(x0.y) << 16);
  o.y = (unsigned)f2bf(x0.z) | ((unsigned)f2bf(x0.w) << 16);
  o.z = (unsigned)f2bf(x1.x) | ((unsigned)f2bf(x1.y) << 16);
  o.w = (unsigned)f2bf(x1.z) | ((unsigned)f2bf(x1.w) << 16);
  ((uint4*)dst)[l] = o;
  #pragma unroll
  for (int off = 32; off > 0; off >>= 1) s += __shfl_down(s, off, 64);
  if (l == 0) {
    if (idx < M_ROWS) nf[idx] = s;
    else              nm[idx - M_ROWS] = s;
  }
}

// ---- Kernel 2: 256x256 8-phase-style bf16 MFMA GEMM (swapped operands) + top-9 ----
// 512 thr / 8 waves; wave (wr=w>>2: n-128-half, wc=w&3: m-64-quarter) owns 128n x 64m.
// mfma_f32_16x16x32_bf16, swapped: C[row=n][col=m], col = lane&15 -> per-thread lists.
// LDS: 4-tile ring (BKT=32) for A(mb) and B(fv), counted vmcnt(8) (2 tiles slack),
// raw s_barrier (no full drains in main loop), per-phase setprio around MFMA cluster.
// XOR swizzle: 16B chunk c of row r stored at c^(r&3); source pre-swizzled, read XORs.
// R0 theory: prev kernel was LDS-read-bound (1.25 b128/MFMA) + 2-phase vmcnt(0) drain
// -> MfmaUtil 25%. This schedule: 0.375 b128/MFMA + loads span phases.
#define MFMA_ROW(AF, NF)                                                          \
  acc[NF][0] = __builtin_amdgcn_mfma_f32_16x16x32_bf16(AF, b0, acc[NF][0], 0, 0, 0); \
  acc[NF][1] = __builtin_amdgcn_mfma_f32_16x16x32_bf16(AF, b1, acc[NF][1], 0, 0, 0); \
  acc[NF][2] = __builtin_amdgcn_mfma_f32_16x16x32_bf16(AF, b2, acc[NF][2], 0, 0, 0); \
  acc[NF][3] = __builtin_amdgcn_mfma_f32_16x16x32_bf16(AF, b3, acc[NF][3], 0, 0, 0);

__global__ __launch_bounds__(512, 2) void gemm_topk_kernel(
    const u16* __restrict__ fvb, const u16* __restrict__ mbb,
    const float* __restrict__ nm, float* __restrict__ partial)
{
  extern __shared__ __align__(16) char smem[];
  u16* const Ab = (u16*)smem;                  // 4 x [256][32] mb tiles (64 KB)
  u16* const Bb = (u16*)(smem + 65536);        // 4 x [256][32] fv tiles (64 KB)
  float* const smerge = (float*)(smem + 131072); // 256*9 floats (9216 B)

  const int t   = threadIdx.x;
  const int l   = t & 63;
  const int w   = t >> 6;        // wave 0..7
  const int wr  = w >> 2;        // n-half (0..1)
  const int wc  = w & 3;         // m-quarter (0..3)
  const int r16 = l & 15;        // frag row-in-16 / m col-in-16
  const int g   = l >> 4;        // k-octet group / C-row group

  const int m0    = blockIdx.x * BMT;
  const int ncoff = blockIdx.y * NPER;

  // staging: per gload instr a wave covers 16 rows (64 B/row); lane l -> row l>>2, chunk l&3
  const int sr4 = l >> 2;
  const int sc4 = ((l & 3) ^ (sr4 & 3)) * 8;    // pre-swizzled source chunk (u16)
  const int ch  = (g ^ (r16 & 3)) * 8;          // swizzled read chunk (u16)
  const int aoff = (wr * 128 + r16) * BKT + ch; // A read base (u16)
  const int boff = (wc * 64 + r16) * BKT + ch;  // B read base (u16)

  float best[4][TOPK];
  float T[4];
  #pragma unroll
  for (int mf = 0; mf < 4; ++mf) {
    T[mf] = 3.4e38f;
    #pragma unroll
    for (int s = 0; s < TOPK; ++s) best[mf][s] = 3.4e38f;
  }

#define STAGE_A(nb, kt_, buf_) do {                                           \
    _Pragma("unroll")                                                         \
    for (int j_ = 0; j_ < 2; ++j_)                                            \
      gload_lds16(mbb + (size_t)((nb) + j_ * 128 + w * 16 + sr4) * KDIM       \
                      + (kt_) * BKT + sc4,                                    \
                  Ab + (buf_) * 8192 + (j_ * 128 + w * 16) * BKT);            \
  } while (0)
#define STAGE_B(kt_, buf_) do {                                               \
    _Pragma("unroll")                                                         \
    for (int j_ = 0; j_ < 2; ++j_)                                            \
      gload_lds16(fvb + (size_t)(m0 + j_ * 128 + w * 16 + sr4) * KDIM         \
                      + (kt_) * BKT + sc4,                                    \
                  Bb + (buf_) * 8192 + (j_ * 128 + w * 16) * BKT);            \
  } while (0)

  // prime the ring: tiles 0,1,2 of first n-tile (12 loads/thread in flight)
  STAGE_A(ncoff, 0, 0); STAGE_B(0, 0);
  STAGE_A(ncoff, 1, 1); STAGE_B(1, 1);
  STAGE_A(ncoff, 2, 2); STAGE_B(2, 2);
  asm volatile("s_waitcnt vmcnt(8)" ::: "memory");   // tile 0 resident
  __builtin_amdgcn_s_barrier();

  for (int nt = 0; nt < NT; ++nt) {
    const int nbase = ncoff + nt * BNT;
    f32x4 acc[8][4];
    #pragma unroll
    for (int nf = 0; nf < 8; ++nf)
      #pragma unroll
      for (int mf = 0; mf < 4; ++mf)
        acc[nf][mf] = (f32x4){0.f, 0.f, 0.f, 0.f};

    #pragma unroll
    for (int kt = 0; kt < KT; ++kt) {
      const u16* Ak = Ab + (kt & 3) * 8192;
      const u16* Bk = Bb + (kt & 3) * 8192;

      // ---------------- phase A: bf[4] + af[0..3], stage A-part of kt+3 ----------------
      bf16x8 b0 = *(const bf16x8*)&Bk[boff +    0];
      bf16x8 b1 = *(const bf16x8*)&Bk[boff +  512];
      bf16x8 b2 = *(const bf16x8*)&Bk[boff + 1024];
      bf16x8 b3 = *(const bf16x8*)&Bk[boff + 1536];
      bf16x8 a0 = *(const bf16x8*)&Ak[aoff +    0];
      bf16x8 a1 = *(const bf16x8*)&Ak[aoff +  512];
      bf16x8 a2 = *(const bf16x8*)&Ak[aoff + 1024];
      bf16x8 a3 = *(const bf16x8*)&Ak[aoff + 1536];
      if (kt < KT - 3) {
        STAGE_A(nbase, kt + 3, (kt + 3) & 3);
      } else if (nt < NT - 1) {
        STAGE_A(nbase + BNT, kt + 3 - KT, (kt + 3) & 3);
      }
      __builtin_amdgcn_s_barrier();
      asm volatile("s_waitcnt lgkmcnt(0)" ::: "memory");
      __builtin_amdgcn_s_setprio(1);
      MFMA_ROW(a0, 0) MFMA_ROW(a1, 1) MFMA_ROW(a2, 2) MFMA_ROW(a3, 3)
      __builtin_amdgcn_s_setprio(0);
      __builtin_amdgcn_s_barrier();

      // ---------------- phase B: af[4..7] (bf reused), stage B-part of kt+3 ------------
      bf16x8 a4 = *(const bf16x8*)&Ak[aoff + 2048];
      bf16x8 a5 = *(const bf16x8*)&Ak[aoff + 2560];
      bf16x8 a6 = *(const bf16x8*)&Ak[aoff + 3072];
      bf16x8 a7 = *(const bf16x8*)&Ak[aoff + 3584];
      if (kt < KT - 3) {
        STAGE_B(kt + 3, (kt + 3) & 3);
      } else if (nt < NT - 1) {
        STAGE_B(kt + 3 - KT, (kt + 3) & 3);
      }
      __builtin_amdgcn_s_barrier();
      asm volatile("s_waitcnt lgkmcnt(0)" ::: "memory");
      __builtin_amdgcn_s_setprio(1);
      MFMA_ROW(a4, 4) MFMA_ROW(a5, 5) MFMA_ROW(a6, 6) MFMA_ROW(a7, 7)
      __builtin_amdgcn_s_setprio(0);
      // end-of-tile counted wait: tile kt+1 must be resident after this barrier.
      // steady state: outstanding = 3 tiles x 4 loads = 12 -> leave 8.
      if (kt < KT - 3) {
        asm volatile("s_waitcnt vmcnt(8)" ::: "memory");
      } else if (kt == KT - 3) {
        if (nt < NT - 1) { asm volatile("s_waitcnt vmcnt(8)" ::: "memory"); }
        else             { asm volatile("s_waitcnt vmcnt(4)" ::: "memory"); }
      } else {
        if (nt < NT - 1) { asm volatile("s_waitcnt vmcnt(8)" ::: "memory"); }
        else             { asm volatile("s_waitcnt vmcnt(0)" ::: "memory"); }
      }
      __builtin_amdgcn_s_barrier();
    }

    // ---- register epilogue: rank = nm[n] - 2*dot (nf[m] deferred to merge kernel) ----
    const float* nmp = nm + nbase + wr * 128 + g * 4;
    #pragma unroll
    for (int nf = 0; nf < 8; ++nf) {
      const float4 q = *(const float4*)(nmp + nf * 16);
      #pragma unroll
      for (int mf = 0; mf < 4; ++mf) {
        float v0 = fmaf(-2.0f, acc[nf][mf][0], q.x);
        float v1 = fmaf(-2.0f, acc[nf][mf][1], q.y);
        float v2 = fmaf(-2.0f, acc[nf][mf][2], q.z);
        float v3 = fmaf(-2.0f, acc[nf][mf][3], q.w);
        float bm = fminf(fminf(v0, v1), fminf(v2, v3));
        if (bm < T[mf]) {
          topk_update(v0, best[mf]);
          topk_update(v1, best[mf]);
          topk_update(v2, best[mf]);
          topk_update(v3, best[mf]);
          T[mf] = best[mf][TOPK - 1];
        }
      }
    }
  }

  // ---- butterfly merge across the 4 lane groups sharing each m column ----
  #pragma unroll
  for (int mf = 0; mf < 4; ++mf) {
    float tmp[TOPK];
    #pragma unroll
    for (int s = 0; s < TOPK; ++s) tmp[s] = __shfl_xor(best[mf][s], 16, 64);
    #pragma unroll
    for (int s = 0; s < TOPK; ++s) topk_update(tmp[s], best[mf]);
    #pragma unroll
    for (int s = 0; s < TOPK; ++s) tmp[s] = __shfl_xor(best[mf][s], 32, 64);
    #pragma unroll
    for (int s = 0; s < TOPK; ++s) topk_update(tmp[s], best[mf]);
  }

  // ---- cross-wave merge: wr=1 waves stash lists, wr=0 waves merge + write ----
  __syncthreads();
  if (wr == 1 && g == 0) {
    #pragma unroll
    for (int mf = 0; mf < 4; ++mf)
      #pragma unroll
      for (int s = 0; s < TOPK; ++s)
        smerge[(wc * 64 + mf * 16 + r16) * TOPK + s] = best[mf][s];
  }
  __syncthreads();
  if (wr == 0) {
    #pragma unroll
    for (int mf = 0; mf < 4; ++mf) {
      const float* p = &smerge[(wc * 64 + mf * 16 + r16) * TOPK];
      #pragma unroll
      for (int s = 0; s < TOPK; ++s) topk_update(p[s], best[mf]);
      const int m = m0 + wc * 64 + mf * 16 + r16;
      float* dst = &partial[((size_t)blockIdx.y * M_ROWS + m) * TOPK];
      if (g == 0)      { dst[0] = best[mf][0]; dst[1] = best[mf][1]; dst[2] = best[mf][2]; }
      else if (g == 1) { dst[3] = best[mf][3]; dst[4] = best[mf][4]; }
      else if (g == 2) { dst[5] = best[mf][5]; dst[6] = best[mf][6]; }
      else             { dst[7] = best[mf][7]; dst[8] = best[mf][8]; }
    }
  }
}

// ---------------- Kernel 3: merge 8 partial lists/row, sqrt, pixel scores ----------------
__global__ __launch_bounds__(256) void merge_kernel(
    const float* __restrict__ partial, const float* __restrict__ nf,
    float* __restrict__ final9, float* __restrict__ out_pix)
{
  int row = blockIdx.x * 256 + threadIdx.x;   // 8192 rows
  float best[TOPK];
  #pragma unroll
  for (int i = 0; i < TOPK; ++i) best[i] = 3.4e38f;
  for (int s = 0; s < NCHUNKS; ++s) {
    const float* p = &partial[((size_t)s * M_ROWS + row) * TOPK];
    #pragma unroll
    for (int i = 0; i < TOPK; ++i) topk_update(p[i], best);
  }
  float nfr = nf[row];
  float d[TOPK];
  #pragma unroll
  for (int i = 0; i < TOPK; ++i) d[i] = sqrtf(fmaxf(best[i] + nfr, 0.0f));
  out_pix[row] = d[0];
  #pragma unroll
  for (int i = 0; i < TOPK; ++i) final9[(size_t)row * TOPK + i] = d[i];
}

// ---------------- Kernel 4: per-image argmax (first-max) + softmax score ----------------
__global__ __launch_bounds__(256) void img_kernel(
    const float* __restrict__ out_pix, const float* __restrict__ final9,
    const int* __restrict__ bptr, float* __restrict__ out_img)
{
  int img = blockIdx.x, t = threadIdx.x;
  float bv = -1.0f; int bi = 0;
  for (int p = t; p < 1024; p += 256) {
    float v = out_pix[img * 1024 + p];
    if (v > bv) { bv = v; bi = p; }
  }
  __shared__ float sv[256];
  __shared__ int   si[256];
  sv[t] = bv; si[t] = bi;
  __syncthreads();
  for (int off = 128; off > 0; off >>= 1) {
    if (t < off) {
      float v2 = sv[t + off]; int i2 = si[t + off];
      if (v2 > sv[t] || (v2 == sv[t] && i2 < si[t])) { sv[t] = v2; si[t] = i2; }
    }
    __syncthreads();
  }
  if (t == 0) {
    int row = img * 1024 + si[0];
    int b = bptr[0];
    float s0 = final9[(size_t)row * TOPK + 0];
    float score = s0;
    if (b > 1) {
      int bb = b < TOPK ? b : TOPK;
      float mx = s0;
      for (int i = 1; i < bb; ++i) mx = fmaxf(mx, final9[(size_t)row * TOPK + i]);
      float den = 0.0f;
      for (int i = 0; i < bb; ++i) den += expf(final9[(size_t)row * TOPK + i] - mx);
      score = s0 * (1.0f - expf(s0 - mx) / den);
    }
    out_img[img] = score;
  }
}

extern "C" void kernel_launch(void* const* d_in, const int* in_sizes, int n_in,
                              void* d_out, int out_size, void* d_ws, size_t ws_size,
                              hipStream_t stream) {
  const float* fv   = (const float*)d_in[0];
  const float* mb   = (const float*)d_in[1];
  const int*   bptr = (const int*)d_in[2];
  float* out = (float*)d_out;

  char* ws = (char*)d_ws;
  u16*   fvb     = (u16*)ws;                       // 8388608 B
  u16*   mbb     = (u16*)(ws + 8388608);           // 16777216 B
  float* nf      = (float*)(ws + 25165824);        // 32768 B
  float* nm      = (float*)(ws + 25198592);        // 65536 B (plain order now)
  float* partial = (float*)(ws + 25264128);        // 8*8192*9*4 = 2359296 B
  float* final9  = (float*)(ws + 27623424);        // 294912 B   (end ~27.9 MB)

  hipLaunchKernelGGL(prep_kernel, dim3((M_ROWS + N_ROWS) / 4), dim3(256), 0, stream,
                     fv, mb, fvb, mbb, nf, nm);
  hipLaunchKernelGGL(gemm_topk_kernel, dim3(M_ROWS / BMT, NCHUNKS), dim3(512),
                     140288, stream, fvb, mbb, nm, partial);
  hipLaunchKernelGGL(merge_kernel, dim3(M_ROWS / 256), dim3(256), 0, stream,
                     partial, nf, final9, out);
  hipLaunchKernelGGL(img_kernel, dim3(8), dim3(256), 0, stream,
                     out, final9, bptr, out + M_ROWS);
}

// Round 2
// 310.054 us; speedup vs baseline: 1.3767x; 1.3767x over previous
//
#include <hip/hip_runtime.h>

typedef unsigned short u16;

#define M_ROWS 8192
#define N_ROWS 16384
#define KDIM   512
#define BM     256
#define BN     128
#define BK     64
#define NCHUNKS 16
#define NPER   (N_ROWS / NCHUNKS)   /* 1024 */
#define TOPK   9

typedef __attribute__((ext_vector_type(8)))  short bf16x8;
typedef __attribute__((ext_vector_type(16))) float f32x16;

__device__ __forceinline__ void gload_lds16(const void* g, void* l) {
  __builtin_amdgcn_global_load_lds(
      (const __attribute__((address_space(1))) void*)g,
      (__attribute__((address_space(3))) void*)l,
      16, 0, 0);
}

__device__ __forceinline__ u16 f2bf(float x) {
  union { float f; unsigned u; } c; c.f = x;
  unsigned u = c.u;
  u += 0x7fffu + ((u >> 16) & 1u);   // RNE; inputs finite randn
  return (u16)(u >> 16);
}

__device__ __forceinline__ void topk_update(float v, float* best) {
  if (v < best[TOPK - 1]) {
    #pragma unroll
    for (int i = 0; i < TOPK; ++i) {
      float b = best[i];
      best[i] = fminf(b, v);
      v = fmaxf(b, v);
    }
  }
}

// ---- Kernel 1: fp32 -> bf16 convert + fp32 row norms; mb norms scattered into
//      MFMA-C-layout permuted order so the GEMM epilogue reads them as broadcasts.
__global__ __launch_bounds__(256) void prep_kernel(
    const float* __restrict__ fv, const float* __restrict__ mb,
    u16* __restrict__ fvb, u16* __restrict__ mbb,
    float* __restrict__ nf, float* __restrict__ nm_perm)
{
  int idx = blockIdx.x * 4 + (threadIdx.x >> 6);   // one wave per row
  int l = threadIdx.x & 63;
  const float* src; u16* dst;
  if (idx < M_ROWS) {
    src = fv + (size_t)idx * KDIM; dst = fvb + (size_t)idx * KDIM;
  } else {
    int r = idx - M_ROWS;
    src = mb + (size_t)r * KDIM; dst = mbb + (size_t)r * KDIM;
  }
  float4 x0 = ((const float4*)src)[2 * l];
  float4 x1 = ((const float4*)src)[2 * l + 1];
  float s = x0.x * x0.x + x0.y * x0.y + x0.z * x0.z + x0.w * x0.w
          + x1.x * x1.x + x1.y * x1.y + x1.z * x1.z + x1.w * x1.w;
  uint4 o;
  o.x = (unsigned)f2bf(x0.x) | ((unsigned)f2bf(x0.y) << 16);
  o.y = (unsigned)f2bf(x0.z) | ((unsigned)f2bf(x0.w) << 16);
  o.z = (unsigned)f2bf(x1.x) | ((unsigned)f2bf(x1.y) << 16);
  o.w = (unsigned)f2bf(x1.z) | ((unsigned)f2bf(x1.w) << 16);
  ((uint4*)dst)[l] = o;
  #pragma unroll
  for (int off = 32; off > 0; off >>= 1) s += __shfl_down(s, off, 64);
  if (l == 0) {
    if (idx < M_ROWS) {
      nf[idx] = s;
    } else {
      // 32x32 C/D: within-tile row w5 = (r&3) + 8*(r>>2) + 4*h  ->  [tile][h][r]
      int n  = idx - M_ROWS;
      int ig = n >> 5;            // global 32-row tile index (512 tiles)
      int w5 = n & 31;
      int h  = (w5 >> 2) & 1;
      int r  = (w5 & 3) | ((w5 >> 3) << 2);
      nm_perm[(ig * 2 + h) * 16 + r] = s;
    }
  }
}

// ---- Kernel 2: bf16 32x32x16 MFMA GEMM (swapped operands) + per-thread top-9 ----
// grid (32, 16), block 256 (4 waves). Block: 256 fv-rows (m) x 1024 mb-rows (n).
// R2 change vs the 314us kernel: each wave owns a 64-wide m-strip (2 x 32 sub-strips)
// -> per kk: 2 fvf + 4 mbf ds_read_b128 feed 8 MFMAs = 0.75 reads/MFMA (was 1.25).
// Same 2-phase schedule, same XOR swizzle, same staging pattern; acc doubles to
// 128 regs (AGPR side), LDS 48 KB (2 blocks/CU), 512 blocks total (2/CU).
// C[row=n][col=m]. Ranked v = nm[n] - 2*dot (nf[m] deferred to merge).
// LDS XOR-swizzle: 16B chunk c of row r stored at chunk c^(r&7); staging permutes
// the per-lane SOURCE k-offset (bijection per row), frag reads XOR the chunk.
__global__ __launch_bounds__(256, 2) void gemm_topk_kernel(
    const u16* __restrict__ fvb, const u16* __restrict__ mbb,
    const float* __restrict__ nm_perm, float* __restrict__ partial)
{
  __shared__ __align__(16) u16 As[BM * BK];     // fv tile [256][64], 32 KB
  __shared__ __align__(16) u16 Bs[BN * BK];     // mb tile [128][64], 16 KB

  const int t   = threadIdx.x;
  const int l   = t & 63;
  const int w   = t >> 6;
  const int h   = l >> 5;        // half-wave
  const int c31 = l & 31;
  const int cx  = c31 & 7;       // frag-read row&7 (both As strips and Bs tiles)

  const int m0    = blockIdx.x * BM;
  const int ncoff = blockIdx.y * NPER;

  // staging: lane l covers row (base + l>>3), chunk l&7; source chunk swizzled
  const int srow_lo = l >> 3;                    // 0..7
  const int sc      = ((l & 7) ^ srow_lo) * 8;   // swizzled source k-offset (u16)

  float best[2][TOPK];
  float T[2];
  #pragma unroll
  for (int s = 0; s < 2; ++s) {
    T[s] = 3.4e38f;
    #pragma unroll
    for (int i = 0; i < TOPK; ++i) best[s][i] = 3.4e38f;
  }

  for (int nt = 0; nt < NPER / BN; ++nt) {
    const int nbase = ncoff + nt * BN;
    f32x16 acc[2][4];
    #pragma unroll
    for (int s = 0; s < 2; ++s)
      #pragma unroll
      for (int i = 0; i < 4; ++i)
        #pragma unroll
        for (int r = 0; r < 16; ++r) acc[s][i][r] = 0.0f;

    for (int kc = 0; kc < KDIM / BK; ++kc) {
      __syncthreads();
      const int kb = kc * BK + sc;
      #pragma unroll
      for (int i = 0; i < 8; ++i)
        gload_lds16(fvb + (size_t)(m0 + w * 64 + i * 8 + srow_lo) * KDIM + kb,
                    &As[(w * 64 + i * 8) * BK]);
      #pragma unroll
      for (int i = 0; i < 4; ++i)
        gload_lds16(mbb + (size_t)(nbase + w * 32 + i * 8 + srow_lo) * KDIM + kb,
                    &Bs[(w * 32 + i * 8) * BK]);
      __syncthreads();
      #pragma unroll
      for (int kk = 0; kk < 4; ++kk) {
        const int ch = ((kk * 2 + h) ^ cx) * 8;              // swizzled chunk (u16)
        bf16x8 f0 = *(const bf16x8*)&As[(w * 64 +      c31) * BK + ch];  // B-op strip 0
        bf16x8 f1 = *(const bf16x8*)&As[(w * 64 + 32 + c31) * BK + ch];  // B-op strip 1
        #pragma unroll
        for (int i = 0; i < 4; ++i) {
          bf16x8 mbf = *(const bf16x8*)&Bs[(i * 32 + c31) * BK + ch]; // A-operand (n)
          acc[0][i] = __builtin_amdgcn_mfma_f32_32x32x16_bf16(mbf, f0, acc[0][i], 0, 0, 0);
          acc[1][i] = __builtin_amdgcn_mfma_f32_32x32x16_bf16(mbf, f1, acc[1][i], 0, 0, 0);
        }
      }
    }

    // ---- register epilogue: two lists per thread; nm in permuted broadcast order ----
    #pragma unroll
    for (int i = 0; i < 4; ++i) {
      const float4* np = (const float4*)&nm_perm[(((nbase >> 5) + i) * 2 + h) * 16];
      float4 q0 = np[0], q1 = np[1], q2 = np[2], q3 = np[3];
      #pragma unroll
      for (int s = 0; s < 2; ++s) {
        float v[16];
        v[ 0] = fmaf(-2.0f, acc[s][i][ 0], q0.x);
        v[ 1] = fmaf(-2.0f, acc[s][i][ 1], q0.y);
        v[ 2] = fmaf(-2.0f, acc[s][i][ 2], q0.z);
        v[ 3] = fmaf(-2.0f, acc[s][i][ 3], q0.w);
        v[ 4] = fmaf(-2.0f, acc[s][i][ 4], q1.x);
        v[ 5] = fmaf(-2.0f, acc[s][i][ 5], q1.y);
        v[ 6] = fmaf(-2.0f, acc[s][i][ 6], q1.z);
        v[ 7] = fmaf(-2.0f, acc[s][i][ 7], q1.w);
        v[ 8] = fmaf(-2.0f, acc[s][i][ 8], q2.x);
        v[ 9] = fmaf(-2.0f, acc[s][i][ 9], q2.y);
        v[10] = fmaf(-2.0f, acc[s][i][10], q2.z);
        v[11] = fmaf(-2.0f, acc[s][i][11], q2.w);
        v[12] = fmaf(-2.0f, acc[s][i][12], q3.x);
        v[13] = fmaf(-2.0f, acc[s][i][13], q3.y);
        v[14] = fmaf(-2.0f, acc[s][i][14], q3.z);
        v[15] = fmaf(-2.0f, acc[s][i][15], q3.w);
        float bmin = 3.4e38f;
        #pragma unroll
        for (int r = 0; r < 16; ++r) bmin = fminf(bmin, v[r]);
        if (bmin < T[s]) {
          #pragma unroll
          for (int r = 0; r < 16; ++r) topk_update(v[r], best[s]);
          T[s] = best[s][TOPK - 1];
        }
      }
    }
    #pragma unroll
    for (int s = 0; s < 2; ++s)
      T[s] = fminf(best[s][TOPK - 1], __shfl_xor(best[s][TOPK - 1], 32, 64));
  }

  // merge the lane pair sharing each m-col (snapshot partner list, then insert)
  #pragma unroll
  for (int s = 0; s < 2; ++s) {
    float tmp[TOPK];
    #pragma unroll
    for (int q = 0; q < TOPK; ++q) tmp[q] = __shfl_xor(best[s][q], 32, 64);
    #pragma unroll
    for (int q = 0; q < TOPK; ++q) topk_update(tmp[q], best[s]);
    int m = m0 + w * 64 + s * 32 + c31;
    size_t base = ((size_t)blockIdx.y * M_ROWS + m) * TOPK;
    if (h == 0) {
      #pragma unroll
      for (int q = 0; q < 5; ++q) partial[base + q] = best[s][q];
    } else {
      #pragma unroll
      for (int q = 5; q < TOPK; ++q) partial[base + q] = best[s][q];
    }
  }
}

// ---------------- Kernel 3: merge 16 partial lists/row, sqrt, pixel scores ----------------
__global__ __launch_bounds__(256) void merge_kernel(
    const float* __restrict__ partial, const float* __restrict__ nf,
    float* __restrict__ final9, float* __restrict__ out_pix)
{
  int row = blockIdx.x * 256 + threadIdx.x;   // 8192 rows
  float best[TOPK];
  #pragma unroll
  for (int i = 0; i < TOPK; ++i) best[i] = 3.4e38f;
  for (int s = 0; s < NCHUNKS; ++s) {
    const float* p = &partial[((size_t)s * M_ROWS + row) * TOPK];
    #pragma unroll
    for (int i = 0; i < TOPK; ++i) topk_update(p[i], best);
  }
  float nfr = nf[row];
  float d[TOPK];
  #pragma unroll
  for (int i = 0; i < TOPK; ++i) d[i] = sqrtf(fmaxf(best[i] + nfr, 0.0f));
  out_pix[row] = d[0];
  #pragma unroll
  for (int i = 0; i < TOPK; ++i) final9[(size_t)row * TOPK + i] = d[i];
}

// ---------------- Kernel 4: per-image argmax (first-max) + softmax score ----------------
__global__ __launch_bounds__(256) void img_kernel(
    const float* __restrict__ out_pix, const float* __restrict__ final9,
    const int* __restrict__ bptr, float* __restrict__ out_img)
{
  int img = blockIdx.x, t = threadIdx.x;
  float bv = -1.0f; int bi = 0;
  for (int p = t; p < 1024; p += 256) {
    float v = out_pix[img * 1024 + p];
    if (v > bv) { bv = v; bi = p; }
  }
  __shared__ float sv[256];
  __shared__ int   si[256];
  sv[t] = bv; si[t] = bi;
  __syncthreads();
  for (int off = 128; off > 0; off >>= 1) {
    if (t < off) {
      float v2 = sv[t + off]; int i2 = si[t + off];
      if (v2 > sv[t] || (v2 == sv[t] && i2 < si[t])) { sv[t] = v2; si[t] = i2; }
    }
    __syncthreads();
  }
  if (t == 0) {
    int row = img * 1024 + si[0];
    int b = bptr[0];
    float s0 = final9[(size_t)row * TOPK + 0];
    float score = s0;
    if (b > 1) {
      int bb = b < TOPK ? b : TOPK;
      float mx = s0;
      for (int i = 1; i < bb; ++i) mx = fmaxf(mx, final9[(size_t)row * TOPK + i]);
      float den = 0.0f;
      for (int i = 0; i < bb; ++i) den += expf(final9[(size_t)row * TOPK + i] - mx);
      score = s0 * (1.0f - expf(s0 - mx) / den);
    }
    out_img[img] = score;
  }
}

extern "C" void kernel_launch(void* const* d_in, const int* in_sizes, int n_in,
                              void* d_out, int out_size, void* d_ws, size_t ws_size,
                              hipStream_t stream) {
  const float* fv   = (const float*)d_in[0];
  const float* mb   = (const float*)d_in[1];
  const int*   bptr = (const int*)d_in[2];
  float* out = (float*)d_out;

  char* ws = (char*)d_ws;
  u16*   fvb     = (u16*)ws;                       // 8388608 B
  u16*   mbb     = (u16*)(ws + 8388608);           // 16777216 B
  float* nf      = (float*)(ws + 25165824);        // 32768 B
  float* nm_perm = (float*)(ws + 25198592);        // 65536 B
  float* partial = (float*)(ws + 25264128);        // 16*8192*9*4 = 4718592 B
  float* final9  = (float*)(ws + 29982720);        // 294912 B   (end ~30.3 MB)

  hipLaunchKernelGGL(prep_kernel, dim3((M_ROWS + N_ROWS) / 4), dim3(256), 0, stream,
                     fv, mb, fvb, mbb, nf, nm_perm);
  hipLaunchKernelGGL(gemm_topk_kernel, dim3(M_ROWS / BM, NCHUNKS), dim3(256), 0, stream,
                     fvb, mbb, nm_perm, partial);
  hipLaunchKernelGGL(merge_kernel, dim3(M_ROWS / 256), dim3(256), 0, stream,
                     partial, nf, final9, out);
  hipLaunchKernelGGL(img_kernel, dim3(8), dim3(256), 0, stream,
                     out, final9, bptr, out + M_ROWS);
}